// Round 12
// baseline (233.508 us; speedup 1.0000x reference)
//
#include <hip/hip_runtime.h>
#include <hip/hip_bf16.h>
#include <stdint.h>

#define N_NODES 50000
#define N_EDGES 800000
#define H_DIM 128
#define N_REL 40
#define N_BASES 4
#define A_COLS 640           // [hbf(128) | S(512)] unified per-node row
#define N_RANGES 196         // node ranges of 256 (dst >> 8)
#define EP_BLOCKS 200        // edge chunks of 4000
#define EDGES_PER_BLK 4000
#define STAGE_CAP 5120       // LDS staging capacity for bucket_sort

typedef __attribute__((ext_vector_type(8))) short bf16x8;
typedef __attribute__((ext_vector_type(4))) float f32x4;

// round-to-nearest-even f32 -> bf16 bits
__device__ __forceinline__ unsigned short f2bf(float f) {
    unsigned int u = __float_as_uint(f);
    unsigned int r = u + 0x7fffu + ((u >> 16) & 1u);
    return (unsigned short)(r >> 16);
}

// ---------------------------------------------------------------------------
// K0 "prep" (fused): blocks 0..3124   -> cast h into A[:,0:128] (bf16)
//                    blocks 3125..3129 -> repack weights into frag-major wt3
//                    blocks 3130..3329 -> edge pack (pkd) + per-(bucket,block)
//                                         histogram (LDS only, no dev atomics)
// pkd[e] = { src | etype<<20 , dst | nbf<<17 }  (nbf = bf16 of norm >= 0)
__global__ __launch_bounds__(256) void prep_kernel(
        const float* __restrict__ h,
        const float* __restrict__ basis_w, const float* __restrict__ loop_w,
        const int* __restrict__ src, const int* __restrict__ dst,
        const int* __restrict__ etype, const float* __restrict__ norm,
        unsigned short* __restrict__ A, unsigned short* __restrict__ wt3,
        uint2* __restrict__ pkd, int* __restrict__ gcnt) {
    int bid = blockIdx.x;
    if (bid < 3125) {
        int t = bid * 256 + threadIdx.x;        // [0, 800000)
        int row = t >> 4;
        int cb = (t & 15) * 8;
        const float* p = h + (size_t)row * 128 + cb;
        float4 a0 = ((const float4*)p)[0];
        float4 a1 = ((const float4*)p)[1];
        bf16x8 o;
        o[0] = (short)f2bf(a0.x); o[1] = (short)f2bf(a0.y);
        o[2] = (short)f2bf(a0.z); o[3] = (short)f2bf(a0.w);
        o[4] = (short)f2bf(a1.x); o[5] = (short)f2bf(a1.y);
        o[6] = (short)f2bf(a1.z); o[7] = (short)f2bf(a1.w);
        *(bf16x8*)(A + (size_t)row * A_COLS + cb) = o;
    } else if (bid < 3130) {
        int mat = bid - 3125;                   // 0..3 basis, 4 loop
        const float* srcm = (mat < 4) ? (basis_w + mat * 16384) : loop_w;
        int koff = (mat < 4) ? (128 + mat * 128) : 0;
        int t = threadIdx.x;
#pragma unroll
        for (int i = 0; i < 16; ++i) {
            int f = t + i * 256;                // [0,4096) float4 index
            int k = f >> 5;
            int j4 = (f & 31) * 4;
            float4 v = ((const float4*)srcm)[f];
            int kg = koff + k;
            int ks = kg >> 5;
            int quad = (kg >> 3) & 3;
            int jj = kg & 7;
            float vv[4] = {v.x, v.y, v.z, v.w};
#pragma unroll
            for (int d = 0; d < 4; ++d) {
                int j = j4 + d;
                int cg = j >> 4;
                int n16 = j & 15;
                wt3[(size_t)((ks * 8 + cg) * 64 + quad * 16 + n16) * 8 + jj] =
                    f2bf(vv[d]);
            }
        }
    } else {
        __shared__ int lhist[N_RANGES];
        int blk = bid - 3130;                   // 0..199
        int t = threadIdx.x;
        if (t < N_RANGES) lhist[t] = 0;
        __syncthreads();
        int e0 = blk * EDGES_PER_BLK;
        for (int i = t; i < EDGES_PER_BLK; i += 256) {
            int e = e0 + i;
            int d = dst[e];
            unsigned int nbf = f2bf(norm[e]);   // <= 0x7FFF (norm >= 0)
            pkd[e] = make_uint2((unsigned)src[e] | ((unsigned)etype[e] << 20),
                                (unsigned)d | (nbf << 17));
            atomicAdd(&lhist[d >> 8], 1);
        }
        __syncthreads();
        if (t < N_RANGES) gcnt[t * EP_BLOCKS + blk] = lhist[t];
    }
}

// K1 (fused scan): blocks 0..195 -> LDS-scan gcnt row r -> RELATIVE blkbase.
//                  block 196     -> thread t sums gcnt row t, scans 196
//                                   totals -> bstart (+ grand total, offs[N]).
// Block 196 runs concurrently with the row-scan blocks (both depend only on
// prep's gcnt).
__global__ __launch_bounds__(256) void bucket_scan(
        const int* __restrict__ gcnt, int* __restrict__ blkbase,
        int* __restrict__ bstart, int* __restrict__ offs) {
    __shared__ int wsum[4];
    int r = blockIdx.x;
    int t = threadIdx.x, lane = t & 63, w = t >> 6;
    if (r < N_RANGES) {
        int x = (t < EP_BLOCKS) ? gcnt[r * EP_BLOCKS + t] : 0;
        int v = x;
#pragma unroll
        for (int d = 1; d < 64; d <<= 1) {
            int y = __shfl_up(v, d);
            if (lane >= d) v += y;
        }
        if (lane == 63) wsum[w] = v;
        __syncthreads();
        int wpre = 0;
        if (w > 0) wpre += wsum[0];
        if (w > 1) wpre += wsum[1];
        if (w > 2) wpre += wsum[2];
        if (t < EP_BLOCKS) blkbase[r * EP_BLOCKS + t] = wpre + v - x;
    } else {
        int tot = 0;
        if (t < N_RANGES) {
            const int* row = gcnt + t * EP_BLOCKS;
#pragma unroll 8
            for (int b = 0; b < EP_BLOCKS; ++b) tot += row[b];
        }
        int v = tot;
#pragma unroll
        for (int d = 1; d < 64; d <<= 1) {
            int y = __shfl_up(v, d);
            if (lane >= d) v += y;
        }
        if (lane == 63) wsum[w] = v;
        __syncthreads();
        int wpre = 0;
        if (w > 0) wpre += wsum[0];
        if (w > 1) wpre += wsum[1];
        if (w > 2) wpre += wsum[2];
        if (t < N_RANGES) bstart[t] = wpre + v - tot;
        if (t == 255) {
            bstart[N_RANGES] = wpre + v;        // = N_EDGES
            offs[N_NODES] = wpre + v;
        }
    }
}

// K2: binscatter. Block b places its 4000 edges into bucket-grouped order.
// Cursor init = bstart[r] + relative blkbase. Each (block,bucket) chunk
// (~20 edges, 160 B) is contiguous -> ~1x write amp.
__global__ __launch_bounds__(256) void binscatter(
        const uint2* __restrict__ pkd, const int* __restrict__ blkbase,
        const int* __restrict__ bstart, uint2* __restrict__ bucketed) {
    __shared__ int lcur[N_RANGES];
    int t = threadIdx.x;
    if (t < N_RANGES)
        lcur[t] = bstart[t] + blkbase[t * EP_BLOCKS + blockIdx.x];
    __syncthreads();
    int e0 = blockIdx.x * EDGES_PER_BLK;
    for (int i = t; i < EDGES_PER_BLK; i += 256) {
        uint2 p = pkd[e0 + i];
        int r = (p.y & 0x1FFFF) >> 8;
        int pos = atomicAdd(&lcur[r], 1);
        bucketed[pos] = p;
    }
}

// K3: bucket_sort. One block per bucket. Pass 1: LDS per-dst histogram ->
// 256-wide LDS scan -> per-dst offsets (offs[node] written coalesced).
// Pass 2: place edges into LDS stage by exact sorted position, then stream
// the region out with fully-coalesced writes. Single-writer output region.
__global__ __launch_bounds__(256) void bucket_sort(
        const int* __restrict__ bstart, const uint2* __restrict__ bucketed,
        uint2* __restrict__ sorted_pe, int* __restrict__ offs) {
    __shared__ int hist[256];
    __shared__ int cur[256];
    __shared__ int wsum[4];
    __shared__ uint2 stage[STAGE_CAP];
    int r = blockIdx.x;
    int t = threadIdx.x, lane = t & 63, w = t >> 6;
    int begin = bstart[r];
    int end = bstart[r + 1];
    int n = end - begin;
    hist[t] = 0;
    __syncthreads();
    for (int i = begin + t; i < end; i += 256)
        atomicAdd(&hist[bucketed[i].y & 255], 1);
    __syncthreads();
    int x = hist[t];
    int v = x;
#pragma unroll
    for (int d = 1; d < 64; d <<= 1) {
        int y = __shfl_up(v, d);
        if (lane >= d) v += y;
    }
    if (lane == 63) wsum[w] = v;
    __syncthreads();
    int wpre = 0;
    if (w > 0) wpre += wsum[0];
    if (w > 1) wpre += wsum[1];
    if (w > 2) wpre += wsum[2];
    int excl_rel = wpre + v - x;                // position within the region
    int node = r * 256 + t;
    if (node < N_NODES) offs[node] = begin + excl_rel;
    cur[t] = excl_rel;
    __syncthreads();
    if (n <= STAGE_CAP) {
        for (int i = begin + t; i < end; i += 256) {
            uint2 p = bucketed[i];
            int pos = atomicAdd(&cur[p.y & 255], 1);
            stage[pos] = make_uint2(p.x, (p.y >> 17) << 16);
        }
        __syncthreads();
        for (int i = t; i < n; i += 256)
            sorted_pe[begin + i] = stage[i];
    } else {                                    // pathological fallback
        for (int i = begin + t; i < end; i += 256) {
            uint2 p = bucketed[i];
            int pos = atomicAdd(&cur[p.y & 255], 1);
            sorted_pe[begin + pos] = make_uint2(p.x, (p.y >> 17) << 16);
        }
    }
}

// K4: per-node aggregation, no atomics. One wave per node; edges processed
// in PAIRS: lanes 0-31 own edge j (channels 4m..4m+3), lanes 32-63 own edge
// j+1 -> one dwordx2 gather per 2 edges (half the VMEM instructions at the
// same bytes). Cross-half shfl_xor(32) reduction at node end.
__global__ __launch_bounds__(256) void aggregate_kernel(
        const int* __restrict__ offs, const uint2* __restrict__ sorted_pe,
        const float* __restrict__ w_comp,
        unsigned short* __restrict__ A) {
    int v = __builtin_amdgcn_readfirstlane(blockIdx.x * 4 + (threadIdx.x >> 6));
    if (v >= N_NODES) return;
    int lane = threadIdx.x & 63;
    int half = lane >> 5;
    int m = lane & 31;
    int begin = offs[v];
    int end = offs[v + 1];

    float acc[4][4];
#pragma unroll
    for (int b = 0; b < 4; ++b)
#pragma unroll
        for (int k = 0; k < 4; ++k) acc[b][k] = 0.f;

    const uint2* Au2 = (const uint2*)A;
    const float4* wcv = (const float4*)w_comp;

    int j = begin;
    for (; j + 8 <= end; j += 8) {              // 4 pairs per batch
        uint2 p[8];
#pragma unroll
        for (int q = 0; q < 8; ++q) p[q] = sorted_pe[j + q];
        uint2 u[4];
#pragma unroll
        for (int q = 0; q < 4; ++q) {
            int sa = p[2 * q].x & 0xFFFFF;
            int sb = p[2 * q + 1].x & 0xFFFFF;
            int ss = half ? sb : sa;
            u[q] = Au2[(size_t)ss * 160 + m];
        }
#pragma unroll
        for (int q = 0; q < 4; ++q) {
            float4 wa = wcv[p[2 * q].x >> 20];
            float4 wb = wcv[p[2 * q + 1].x >> 20];
            float na = __uint_as_float(p[2 * q].y);
            float nb = __uint_as_float(p[2 * q + 1].y);
            float4 wsel = half ? wb : wa;
            float nsel = half ? nb : na;
            float c0 = wsel.x * nsel, c1 = wsel.y * nsel;
            float c2 = wsel.z * nsel, c3 = wsel.w * nsel;
            float l0 = __uint_as_float(u[q].x << 16);
            float h0 = __uint_as_float(u[q].x & 0xffff0000u);
            float l1 = __uint_as_float(u[q].y << 16);
            float h1 = __uint_as_float(u[q].y & 0xffff0000u);
            acc[0][0] += c0 * l0; acc[0][1] += c0 * h0; acc[0][2] += c0 * l1; acc[0][3] += c0 * h1;
            acc[1][0] += c1 * l0; acc[1][1] += c1 * h0; acc[1][2] += c1 * l1; acc[1][3] += c1 * h1;
            acc[2][0] += c2 * l0; acc[2][1] += c2 * h0; acc[2][2] += c2 * l1; acc[2][3] += c2 * h1;
            acc[3][0] += c3 * l0; acc[3][1] += c3 * h0; acc[3][2] += c3 * l1; acc[3][3] += c3 * h1;
        }
    }
    for (; j + 2 <= end; j += 2) {              // remaining full pairs
        uint2 p0 = sorted_pe[j], p1 = sorted_pe[j + 1];
        int sa = p0.x & 0xFFFFF, sb = p1.x & 0xFFFFF;
        int ss = half ? sb : sa;
        uint2 u = Au2[(size_t)ss * 160 + m];
        float4 wa = wcv[p0.x >> 20], wb = wcv[p1.x >> 20];
        float na = __uint_as_float(p0.y), nb = __uint_as_float(p1.y);
        float4 wsel = half ? wb : wa;
        float nsel = half ? nb : na;
        float c0 = wsel.x * nsel, c1 = wsel.y * nsel;
        float c2 = wsel.z * nsel, c3 = wsel.w * nsel;
        float l0 = __uint_as_float(u.x << 16);
        float h0 = __uint_as_float(u.x & 0xffff0000u);
        float l1 = __uint_as_float(u.y << 16);
        float h1 = __uint_as_float(u.y & 0xffff0000u);
        acc[0][0] += c0 * l0; acc[0][1] += c0 * h0; acc[0][2] += c0 * l1; acc[0][3] += c0 * h1;
        acc[1][0] += c1 * l0; acc[1][1] += c1 * h0; acc[1][2] += c1 * l1; acc[1][3] += c1 * h1;
        acc[2][0] += c2 * l0; acc[2][1] += c2 * h0; acc[2][2] += c2 * l1; acc[2][3] += c2 * h1;
        acc[3][0] += c3 * l0; acc[3][1] += c3 * h0; acc[3][2] += c3 * l1; acc[3][3] += c3 * h1;
    }
    if (j < end) {                              // odd tail edge: half 1 -> 0
        uint2 p0 = sorted_pe[j];
        int ss = p0.x & 0xFFFFF;
        uint2 u = Au2[(size_t)ss * 160 + m];
        float4 wa = wcv[p0.x >> 20];
        float nsel = half ? 0.f : __uint_as_float(p0.y);
        float c0 = wa.x * nsel, c1 = wa.y * nsel;
        float c2 = wa.z * nsel, c3 = wa.w * nsel;
        float l0 = __uint_as_float(u.x << 16);
        float h0 = __uint_as_float(u.x & 0xffff0000u);
        float l1 = __uint_as_float(u.y << 16);
        float h1 = __uint_as_float(u.y & 0xffff0000u);
        acc[0][0] += c0 * l0; acc[0][1] += c0 * h0; acc[0][2] += c0 * l1; acc[0][3] += c0 * h1;
        acc[1][0] += c1 * l0; acc[1][1] += c1 * h0; acc[1][2] += c1 * l1; acc[1][3] += c1 * h1;
        acc[2][0] += c2 * l0; acc[2][1] += c2 * h0; acc[2][2] += c2 * l1; acc[2][3] += c2 * h1;
        acc[3][0] += c3 * l0; acc[3][1] += c3 * h0; acc[3][2] += c3 * l1; acc[3][3] += c3 * h1;
    }

    // combine halves (each half holds the other half's edges' contributions)
#pragma unroll
    for (int b = 0; b < 4; ++b)
#pragma unroll
        for (int k = 0; k < 4; ++k)
            acc[b][k] += __shfl_xor(acc[b][k], 32);

    // write S: lanes 0-31 write bases 0,1; lanes 32-63 write bases 2,3.
    uint2* ps2 = (uint2*)A + (size_t)v * 160 + 32;
#pragma unroll
    for (int bb = 0; bb < 2; ++bb) {
        int b = half * 2 + bb;
        uint2 o;
        o.x = (unsigned int)f2bf(acc[b][0]) | ((unsigned int)f2bf(acc[b][1]) << 16);
        o.y = (unsigned int)f2bf(acc[b][2]) | ((unsigned int)f2bf(acc[b][3]) << 16);
        ps2[b * 32 + m] = o;
    }
}

// K5: out = relu(bias + A @ Wstack)   (M=50048, N=128, K=640 bf16 MFMA GEMM)
// v4: ONE wave per block (32 rows x 128 cols), grid 1564 -> 6.1 blocks/CU,
// fine-grained tail (vs 391 blocks = 1.53/CU with 2x serialization on half
// the CUs). A streamed exactly once; B frag-major coalesced; 2-deep register
// prefetch.
__global__ __launch_bounds__(64) void gemm_out(
        const unsigned short* __restrict__ A,
        const unsigned short* __restrict__ wt3,
        const float* __restrict__ bias,
        float* __restrict__ out) {
    int lane = threadIdx.x;
    int n16 = lane & 15;
    int quad = lane >> 4;
    int r0 = blockIdx.x * 32;

    const unsigned short* ap0 = A + (size_t)(r0 + n16) * A_COLS + quad * 8;
    const unsigned short* ap1 = ap0 + 16 * A_COLS;
    const unsigned short* bp = wt3 + (size_t)lane * 8;

    f32x4 acc[2][8];
#pragma unroll
    for (int rt = 0; rt < 2; ++rt)
#pragma unroll
        for (int ct = 0; ct < 8; ++ct)
            acc[rt][ct] = (f32x4)0.f;

    bf16x8 a_cur[2], b_cur[8];
    a_cur[0] = *(const bf16x8*)ap0;
    a_cur[1] = *(const bf16x8*)ap1;
#pragma unroll
    for (int ct = 0; ct < 8; ++ct)
        b_cur[ct] = *(const bf16x8*)(bp + ct * 512);

#pragma unroll
    for (int ks = 0; ks < 20; ++ks) {
        bf16x8 a_nxt[2], b_nxt[8];
        if (ks < 19) {
            a_nxt[0] = *(const bf16x8*)(ap0 + (ks + 1) * 32);
            a_nxt[1] = *(const bf16x8*)(ap1 + (ks + 1) * 32);
#pragma unroll
            for (int ct = 0; ct < 8; ++ct)
                b_nxt[ct] = *(const bf16x8*)(bp + (ks + 1) * 4096 + ct * 512);
        } else {
            a_nxt[0] = a_cur[0];
            a_nxt[1] = a_cur[1];
#pragma unroll
            for (int ct = 0; ct < 8; ++ct) b_nxt[ct] = b_cur[ct];
        }
#pragma unroll
        for (int ct = 0; ct < 8; ++ct) {
            acc[0][ct] = __builtin_amdgcn_mfma_f32_16x16x32_bf16(a_cur[0], b_cur[ct], acc[0][ct], 0, 0, 0);
            acc[1][ct] = __builtin_amdgcn_mfma_f32_16x16x32_bf16(a_cur[1], b_cur[ct], acc[1][ct], 0, 0, 0);
        }
        a_cur[0] = a_nxt[0];
        a_cur[1] = a_nxt[1];
#pragma unroll
        for (int ct = 0; ct < 8; ++ct) b_cur[ct] = b_nxt[ct];
    }

    // C/D layout: col = lane&15, row = quad*4 + reg
#pragma unroll
    for (int rt = 0; rt < 2; ++rt) {
        int rbase = r0 + rt * 16 + quad * 4;
#pragma unroll
        for (int ct = 0; ct < 8; ++ct) {
            int col = ct * 16 + n16;
            float bv = bias[col];
#pragma unroll
            for (int rg = 0; rg < 4; ++rg) {
                int r = rbase + rg;
                if (r < N_NODES)
                    out[(size_t)r * H_DIM + col] = fmaxf(acc[rt][ct][rg] + bv, 0.f);
            }
        }
    }
}

extern "C" void kernel_launch(void* const* d_in, const int* in_sizes, int n_in,
                              void* d_out, int out_size, void* d_ws, size_t ws_size,
                              hipStream_t stream) {
    const float* h       = (const float*)d_in[0];
    const float* norm    = (const float*)d_in[1];
    const float* basis_w = (const float*)d_in[2];
    const float* w_comp  = (const float*)d_in[3];
    const float* loop_w  = (const float*)d_in[4];
    const float* bias    = (const float*)d_in[5];
    const int*   src     = (const int*)d_in[6];
    const int*   dst     = (const int*)d_in[7];
    const int*   etype   = (const int*)d_in[8];
    float* out = (float*)d_out;

    // ws layout (bytes):
    char* base = (char*)d_ws;
    unsigned short* wt3       = (unsigned short*)(base + 0);          //    163,840
    unsigned short* A         = (unsigned short*)(base + 163840);     // 64,061,440
    int*            offs      = (int*)(base + 64225280);              //    200,064
    uint2*          pkd       = (uint2*)(base + 64425344);            //  6,400,000
    uint2*          bucketed  = (uint2*)(base + 70825344);            //  6,400,000
    uint2*          sorted_pe = (uint2*)(base + 77225344);            //  6,400,000
    int*            gcnt      = (int*)(base + 83625344);              //    156,800
    int*            blkbase   = (int*)(base + 83782144);              //    156,800
    int*            bstart    = (int*)(base + 83938944);              //        788
    // total ~84 MB

    prep_kernel<<<3330, 256, 0, stream>>>(h, basis_w, loop_w,
                                          src, dst, etype, norm,
                                          A, wt3, pkd, gcnt);
    bucket_scan<<<N_RANGES + 1, 256, 0, stream>>>(gcnt, blkbase, bstart, offs);
    binscatter<<<EP_BLOCKS, 256, 0, stream>>>(pkd, blkbase, bstart, bucketed);
    bucket_sort<<<N_RANGES, 256, 0, stream>>>(bstart, bucketed, sorted_pe, offs);
    aggregate_kernel<<<12500, 256, 0, stream>>>(offs, sorted_pe, w_comp, A);
    gemm_out<<<1564, 64, 0, stream>>>(A, wt3, bias, out);
}

// Round 13
// 204.590 us; speedup vs baseline: 1.1413x; 1.1413x over previous
//
#include <hip/hip_runtime.h>
#include <hip/hip_bf16.h>
#include <stdint.h>

#define N_NODES 50000
#define N_EDGES 800000
#define H_DIM 128
#define N_REL 40
#define N_BASES 4
#define A_COLS 640           // [hbf(128) | S(512)] unified per-node row
#define N_RANGES 196         // node ranges of 256 (dst >> 8)
#define EP_BLOCKS 200        // edge chunks of 4000
#define EDGES_PER_BLK 4000
#define STAGE_CAP 5120       // LDS staging capacity for bucket_sort

typedef __attribute__((ext_vector_type(8))) short bf16x8;
typedef __attribute__((ext_vector_type(4))) float f32x4;

// round-to-nearest-even f32 -> bf16 bits
__device__ __forceinline__ unsigned short f2bf(float f) {
    unsigned int u = __float_as_uint(f);
    unsigned int r = u + 0x7fffu + ((u >> 16) & 1u);
    return (unsigned short)(r >> 16);
}

// ---------------------------------------------------------------------------
// K0 "prep" (fused): blocks 0..3124   -> cast h into A[:,0:128] (bf16)
//                    blocks 3125..3129 -> repack weights into frag-major wt3
//                    blocks 3130..3329 -> edge pack (pkd) + per-(bucket,block)
//                                         histogram (LDS only, no dev atomics)
// pkd[e] = { src | etype<<20 , dst | nbf<<17 }  (nbf = bf16 of norm >= 0)
__global__ __launch_bounds__(256) void prep_kernel(
        const float* __restrict__ h,
        const float* __restrict__ basis_w, const float* __restrict__ loop_w,
        const int* __restrict__ src, const int* __restrict__ dst,
        const int* __restrict__ etype, const float* __restrict__ norm,
        unsigned short* __restrict__ A, unsigned short* __restrict__ wt3,
        uint2* __restrict__ pkd, int* __restrict__ gcnt) {
    int bid = blockIdx.x;
    if (bid < 3125) {
        int t = bid * 256 + threadIdx.x;        // [0, 800000)
        int row = t >> 4;
        int cb = (t & 15) * 8;
        const float* p = h + (size_t)row * 128 + cb;
        float4 a0 = ((const float4*)p)[0];
        float4 a1 = ((const float4*)p)[1];
        bf16x8 o;
        o[0] = (short)f2bf(a0.x); o[1] = (short)f2bf(a0.y);
        o[2] = (short)f2bf(a0.z); o[3] = (short)f2bf(a0.w);
        o[4] = (short)f2bf(a1.x); o[5] = (short)f2bf(a1.y);
        o[6] = (short)f2bf(a1.z); o[7] = (short)f2bf(a1.w);
        *(bf16x8*)(A + (size_t)row * A_COLS + cb) = o;
    } else if (bid < 3130) {
        int mat = bid - 3125;                   // 0..3 basis, 4 loop
        const float* srcm = (mat < 4) ? (basis_w + mat * 16384) : loop_w;
        int koff = (mat < 4) ? (128 + mat * 128) : 0;
        int t = threadIdx.x;
#pragma unroll
        for (int i = 0; i < 16; ++i) {
            int f = t + i * 256;                // [0,4096) float4 index
            int k = f >> 5;
            int j4 = (f & 31) * 4;
            float4 v = ((const float4*)srcm)[f];
            int kg = koff + k;
            int ks = kg >> 5;
            int quad = (kg >> 3) & 3;
            int jj = kg & 7;
            float vv[4] = {v.x, v.y, v.z, v.w};
#pragma unroll
            for (int d = 0; d < 4; ++d) {
                int j = j4 + d;
                int cg = j >> 4;
                int n16 = j & 15;
                wt3[(size_t)((ks * 8 + cg) * 64 + quad * 16 + n16) * 8 + jj] =
                    f2bf(vv[d]);
            }
        }
    } else {
        __shared__ int lhist[N_RANGES];
        int blk = bid - 3130;                   // 0..199
        int t = threadIdx.x;
        if (t < N_RANGES) lhist[t] = 0;
        __syncthreads();
        int e0 = blk * EDGES_PER_BLK;
        for (int i = t; i < EDGES_PER_BLK; i += 256) {
            int e = e0 + i;
            int d = dst[e];
            unsigned int nbf = f2bf(norm[e]);   // <= 0x7FFF (norm >= 0)
            pkd[e] = make_uint2((unsigned)src[e] | ((unsigned)etype[e] << 20),
                                (unsigned)d | (nbf << 17));
            atomicAdd(&lhist[d >> 8], 1);
        }
        __syncthreads();
        if (t < N_RANGES) gcnt[t * EP_BLOCKS + blk] = lhist[t];
    }
}

// K1 (fused scan): blocks 0..195 -> LDS-scan gcnt row r -> RELATIVE blkbase.
//                  block 196     -> thread t sums gcnt row t, scans 196
//                                   totals -> bstart (+ grand total, offs[N]).
__global__ __launch_bounds__(256) void bucket_scan(
        const int* __restrict__ gcnt, int* __restrict__ blkbase,
        int* __restrict__ bstart, int* __restrict__ offs) {
    __shared__ int wsum[4];
    int r = blockIdx.x;
    int t = threadIdx.x, lane = t & 63, w = t >> 6;
    if (r < N_RANGES) {
        int x = (t < EP_BLOCKS) ? gcnt[r * EP_BLOCKS + t] : 0;
        int v = x;
#pragma unroll
        for (int d = 1; d < 64; d <<= 1) {
            int y = __shfl_up(v, d);
            if (lane >= d) v += y;
        }
        if (lane == 63) wsum[w] = v;
        __syncthreads();
        int wpre = 0;
        if (w > 0) wpre += wsum[0];
        if (w > 1) wpre += wsum[1];
        if (w > 2) wpre += wsum[2];
        if (t < EP_BLOCKS) blkbase[r * EP_BLOCKS + t] = wpre + v - x;
    } else {
        int tot = 0;
        if (t < N_RANGES) {
            const int* row = gcnt + t * EP_BLOCKS;
#pragma unroll 8
            for (int b = 0; b < EP_BLOCKS; ++b) tot += row[b];
        }
        int v = tot;
#pragma unroll
        for (int d = 1; d < 64; d <<= 1) {
            int y = __shfl_up(v, d);
            if (lane >= d) v += y;
        }
        if (lane == 63) wsum[w] = v;
        __syncthreads();
        int wpre = 0;
        if (w > 0) wpre += wsum[0];
        if (w > 1) wpre += wsum[1];
        if (w > 2) wpre += wsum[2];
        if (t < N_RANGES) bstart[t] = wpre + v - tot;
        if (t == 255) {
            bstart[N_RANGES] = wpre + v;        // = N_EDGES
            offs[N_NODES] = wpre + v;
        }
    }
}

// K2: binscatter. Block b places its 4000 edges into bucket-grouped order.
// Cursor init = bstart[r] + relative blkbase. Each (block,bucket) chunk
// (~20 edges, 160 B) is contiguous -> ~1x write amp.
__global__ __launch_bounds__(256) void binscatter(
        const uint2* __restrict__ pkd, const int* __restrict__ blkbase,
        const int* __restrict__ bstart, uint2* __restrict__ bucketed) {
    __shared__ int lcur[N_RANGES];
    int t = threadIdx.x;
    if (t < N_RANGES)
        lcur[t] = bstart[t] + blkbase[t * EP_BLOCKS + blockIdx.x];
    __syncthreads();
    int e0 = blockIdx.x * EDGES_PER_BLK;
    for (int i = t; i < EDGES_PER_BLK; i += 256) {
        uint2 p = pkd[e0 + i];
        int r = (p.y & 0x1FFFF) >> 8;
        int pos = atomicAdd(&lcur[r], 1);
        bucketed[pos] = p;
    }
}

// K3: bucket_sort. One block per bucket. Pass 1: LDS per-dst histogram ->
// 256-wide LDS scan -> per-dst offsets (offs[node] written coalesced).
// Pass 2: place edges into LDS stage by exact sorted position, then stream
// the region out with fully-coalesced writes. Single-writer output region.
__global__ __launch_bounds__(256) void bucket_sort(
        const int* __restrict__ bstart, const uint2* __restrict__ bucketed,
        uint2* __restrict__ sorted_pe, int* __restrict__ offs) {
    __shared__ int hist[256];
    __shared__ int cur[256];
    __shared__ int wsum[4];
    __shared__ uint2 stage[STAGE_CAP];
    int r = blockIdx.x;
    int t = threadIdx.x, lane = t & 63, w = t >> 6;
    int begin = bstart[r];
    int end = bstart[r + 1];
    int n = end - begin;
    hist[t] = 0;
    __syncthreads();
    for (int i = begin + t; i < end; i += 256)
        atomicAdd(&hist[bucketed[i].y & 255], 1);
    __syncthreads();
    int x = hist[t];
    int v = x;
#pragma unroll
    for (int d = 1; d < 64; d <<= 1) {
        int y = __shfl_up(v, d);
        if (lane >= d) v += y;
    }
    if (lane == 63) wsum[w] = v;
    __syncthreads();
    int wpre = 0;
    if (w > 0) wpre += wsum[0];
    if (w > 1) wpre += wsum[1];
    if (w > 2) wpre += wsum[2];
    int excl_rel = wpre + v - x;                // position within the region
    int node = r * 256 + t;
    if (node < N_NODES) offs[node] = begin + excl_rel;
    cur[t] = excl_rel;
    __syncthreads();
    if (n <= STAGE_CAP) {
        for (int i = begin + t; i < end; i += 256) {
            uint2 p = bucketed[i];
            int pos = atomicAdd(&cur[p.y & 255], 1);
            stage[pos] = make_uint2(p.x, (p.y >> 17) << 16);
        }
        __syncthreads();
        for (int i = t; i < n; i += 256)
            sorted_pe[begin + i] = stage[i];
    } else {                                    // pathological fallback
        for (int i = begin + t; i < end; i += 256) {
            uint2 p = bucketed[i];
            int pos = atomicAdd(&cur[p.y & 255], 1);
            sorted_pe[begin + pos] = make_uint2(p.x, (p.y >> 17) << 16);
        }
    }
}

// K4: per-node aggregation, no atomics. One wave per node; edge metadata is
// wave-uniform -> scalar loads (8-wide batches); gather is one 256B row per
// edge (4B/lane), 8 outstanding. A[v][128+b*128+c] = sum cf[b]*A[src][c].
// (r11 version — r12's edge-pairing variant was VALU-bound, reverted.)
__global__ __launch_bounds__(256) void aggregate_kernel(
        const int* __restrict__ offs, const uint2* __restrict__ sorted_pe,
        const float* __restrict__ w_comp,
        unsigned short* __restrict__ A) {
    int v = __builtin_amdgcn_readfirstlane(blockIdx.x * 4 + (threadIdx.x >> 6));
    if (v >= N_NODES) return;
    int lane = threadIdx.x & 63;
    int begin = offs[v];
    int end = offs[v + 1];

    float a0l = 0.f, a0h = 0.f, a1l = 0.f, a1h = 0.f;
    float a2l = 0.f, a2h = 0.f, a3l = 0.f, a3h = 0.f;

    const unsigned int* Au = (const unsigned int*)A;

    int j = begin;
    for (; j + 8 <= end; j += 8) {
        uint2 p[8];
        unsigned int u[8];
#pragma unroll
        for (int q = 0; q < 8; ++q) p[q] = sorted_pe[j + q];
#pragma unroll
        for (int q = 0; q < 8; ++q)
            u[q] = Au[(size_t)(p[q].x & 0xFFFFF) * 320 + lane];
#pragma unroll
        for (int q = 0; q < 8; ++q) {
            float4 wc = ((const float4*)w_comp)[p[q].x >> 20];
            float nm = __uint_as_float(p[q].y);
            float lo = __uint_as_float(u[q] << 16);
            float hi = __uint_as_float(u[q] & 0xffff0000u);
            a0l += (wc.x * nm) * lo; a0h += (wc.x * nm) * hi;
            a1l += (wc.y * nm) * lo; a1h += (wc.y * nm) * hi;
            a2l += (wc.z * nm) * lo; a2h += (wc.z * nm) * hi;
            a3l += (wc.w * nm) * lo; a3h += (wc.w * nm) * hi;
        }
    }
    for (; j < end; ++j) {
        uint2 p = sorted_pe[j];
        int s = p.x & 0xFFFFF;
        float4 wc = ((const float4*)w_comp)[p.x >> 20];
        float nm = __uint_as_float(p.y);
        unsigned int u = Au[(size_t)s * 320 + lane];
        float lo = __uint_as_float(u << 16);
        float hi = __uint_as_float(u & 0xffff0000u);
        a0l += (wc.x * nm) * lo; a0h += (wc.x * nm) * hi;
        a1l += (wc.y * nm) * lo; a1h += (wc.y * nm) * hi;
        a2l += (wc.z * nm) * lo; a2h += (wc.z * nm) * hi;
        a3l += (wc.w * nm) * lo; a3h += (wc.w * nm) * hi;
    }

    unsigned int* ps = (unsigned int*)(A + (size_t)v * A_COLS + 128);
    ps[0 * 64 + lane] = (unsigned int)f2bf(a0l) | ((unsigned int)f2bf(a0h) << 16);
    ps[1 * 64 + lane] = (unsigned int)f2bf(a1l) | ((unsigned int)f2bf(a1h) << 16);
    ps[2 * 64 + lane] = (unsigned int)f2bf(a2l) | ((unsigned int)f2bf(a2h) << 16);
    ps[3 * 64 + lane] = (unsigned int)f2bf(a3l) | ((unsigned int)f2bf(a3h) << 16);
}

// K5: out = relu(bias + A @ Wstack)   (M=50048, N=128, K=640 bf16 MFMA GEMM)
// v3 (r11, reverted from r12's 1-wave blocks): wave = 32 rows x 128 cols,
// block = 4 waves (sharing wt3 in L1), grid = 391. A streamed exactly once;
// B frag-major coalesced; 2-deep register prefetch.
__global__ __launch_bounds__(256, 2) void gemm_out(
        const unsigned short* __restrict__ A,
        const unsigned short* __restrict__ wt3,
        const float* __restrict__ bias,
        float* __restrict__ out) {
    int wv = threadIdx.x >> 6;
    int lane = threadIdx.x & 63;
    int n16 = lane & 15;
    int quad = lane >> 4;
    int r0 = (blockIdx.x * 4 + wv) * 32;

    const unsigned short* ap0 = A + (size_t)(r0 + n16) * A_COLS + quad * 8;
    const unsigned short* ap1 = ap0 + 16 * A_COLS;
    const unsigned short* bp = wt3 + (size_t)lane * 8;

    f32x4 acc[2][8];
#pragma unroll
    for (int rt = 0; rt < 2; ++rt)
#pragma unroll
        for (int ct = 0; ct < 8; ++ct)
            acc[rt][ct] = (f32x4)0.f;

    bf16x8 a_cur[2], b_cur[8];
    a_cur[0] = *(const bf16x8*)ap0;
    a_cur[1] = *(const bf16x8*)ap1;
#pragma unroll
    for (int ct = 0; ct < 8; ++ct)
        b_cur[ct] = *(const bf16x8*)(bp + ct * 512);

#pragma unroll
    for (int ks = 0; ks < 20; ++ks) {
        bf16x8 a_nxt[2], b_nxt[8];
        if (ks < 19) {
            a_nxt[0] = *(const bf16x8*)(ap0 + (ks + 1) * 32);
            a_nxt[1] = *(const bf16x8*)(ap1 + (ks + 1) * 32);
#pragma unroll
            for (int ct = 0; ct < 8; ++ct)
                b_nxt[ct] = *(const bf16x8*)(bp + (ks + 1) * 4096 + ct * 512);
        } else {
            a_nxt[0] = a_cur[0];
            a_nxt[1] = a_cur[1];
#pragma unroll
            for (int ct = 0; ct < 8; ++ct) b_nxt[ct] = b_cur[ct];
        }
#pragma unroll
        for (int ct = 0; ct < 8; ++ct) {
            acc[0][ct] = __builtin_amdgcn_mfma_f32_16x16x32_bf16(a_cur[0], b_cur[ct], acc[0][ct], 0, 0, 0);
            acc[1][ct] = __builtin_amdgcn_mfma_f32_16x16x32_bf16(a_cur[1], b_cur[ct], acc[1][ct], 0, 0, 0);
        }
        a_cur[0] = a_nxt[0];
        a_cur[1] = a_nxt[1];
#pragma unroll
        for (int ct = 0; ct < 8; ++ct) b_cur[ct] = b_nxt[ct];
    }

    // C/D layout: col = lane&15, row = quad*4 + reg
#pragma unroll
    for (int rt = 0; rt < 2; ++rt) {
        int rbase = r0 + rt * 16 + quad * 4;
#pragma unroll
        for (int ct = 0; ct < 8; ++ct) {
            int col = ct * 16 + n16;
            float bv = bias[col];
#pragma unroll
            for (int rg = 0; rg < 4; ++rg) {
                int r = rbase + rg;
                if (r < N_NODES)
                    out[(size_t)r * H_DIM + col] = fmaxf(acc[rt][ct][rg] + bv, 0.f);
            }
        }
    }
}

extern "C" void kernel_launch(void* const* d_in, const int* in_sizes, int n_in,
                              void* d_out, int out_size, void* d_ws, size_t ws_size,
                              hipStream_t stream) {
    const float* h       = (const float*)d_in[0];
    const float* norm    = (const float*)d_in[1];
    const float* basis_w = (const float*)d_in[2];
    const float* w_comp  = (const float*)d_in[3];
    const float* loop_w  = (const float*)d_in[4];
    const float* bias    = (const float*)d_in[5];
    const int*   src     = (const int*)d_in[6];
    const int*   dst     = (const int*)d_in[7];
    const int*   etype   = (const int*)d_in[8];
    float* out = (float*)d_out;

    // ws layout (bytes):
    char* base = (char*)d_ws;
    unsigned short* wt3       = (unsigned short*)(base + 0);          //    163,840
    unsigned short* A         = (unsigned short*)(base + 163840);     // 64,061,440
    int*            offs      = (int*)(base + 64225280);              //    200,064
    uint2*          pkd       = (uint2*)(base + 64425344);            //  6,400,000
    uint2*          bucketed  = (uint2*)(base + 70825344);            //  6,400,000
    uint2*          sorted_pe = (uint2*)(base + 77225344);            //  6,400,000
    int*            gcnt      = (int*)(base + 83625344);              //    156,800
    int*            blkbase   = (int*)(base + 83782144);              //    156,800
    int*            bstart    = (int*)(base + 83938944);              //        788
    // total ~84 MB

    prep_kernel<<<3330, 256, 0, stream>>>(h, basis_w, loop_w,
                                          src, dst, etype, norm,
                                          A, wt3, pkd, gcnt);
    bucket_scan<<<N_RANGES + 1, 256, 0, stream>>>(gcnt, blkbase, bstart, offs);
    binscatter<<<EP_BLOCKS, 256, 0, stream>>>(pkd, blkbase, bstart, bucketed);
    bucket_sort<<<N_RANGES, 256, 0, stream>>>(bstart, bucketed, sorted_pe, offs);
    aggregate_kernel<<<12500, 256, 0, stream>>>(offs, sorted_pe, w_comp, A);
    gemm_out<<<391, 256, 0, stream>>>(A, wt3, bias, out);
}